// Round 1
// baseline (80.274 us; speedup 1.0000x reference)
//
#include <hip/hip_runtime.h>

// Median blur 3x3, zero-padded, input (8,3,512,512) fp32 -> same shape.
// One thread computes 4 contiguous output pixels (float4 aligned).

#define MB_W 512
#define MB_H 512
#define MB_PLANES (8 * 3)                 // B*C contiguous planes
#define MB_ROWS (MB_PLANES * MB_H)        // 12288 rows of 512 floats
#define MB_THREADS (MB_ROWS * (MB_W / 4)) // one float4 per thread

__device__ __forceinline__ float median9(float p0, float p1, float p2,
                                         float p3, float p4, float p5,
                                         float p6, float p7, float p8) {
    // Paeth's 19-compare-exchange median-of-9 network.
#define CE(a, b) { float t_ = fminf(a, b); b = fmaxf(a, b); a = t_; }
    CE(p1, p2); CE(p4, p5); CE(p7, p8);
    CE(p0, p1); CE(p3, p4); CE(p6, p7);
    CE(p1, p2); CE(p4, p5); CE(p7, p8);
    CE(p0, p3); CE(p5, p8); CE(p4, p7);
    CE(p3, p6); CE(p1, p4); CE(p2, p5);
    CE(p4, p7); CE(p4, p2); CE(p6, p4);
    CE(p4, p2);
#undef CE
    return p4;
}

__global__ __launch_bounds__(256) void median_blur_kernel(
        const float* __restrict__ in, float* __restrict__ out) {
    const int gid = blockIdx.x * blockDim.x + threadIdx.x;
    const int xq = gid & 127;      // x / 4 within row (W/4 = 128)
    const int r  = gid >> 7;       // global row index in [0, MB_ROWS)
    const int y  = r & (MB_H - 1); // row within plane
    const int x0 = xq << 2;        // first pixel x of this thread

    const float* rowc = in + (size_t)r * MB_W;

    // a[dy][k]: k=0 is x0-1, k=1..4 are x0..x0+3, k=5 is x0+4 (zero-padded).
    float a[3][6];
    #pragma unroll
    for (int dy = 0; dy < 3; ++dy) {
        const int yy = y + dy - 1;
        const float* rp = rowc + (ptrdiff_t)(dy - 1) * MB_W;
        if (yy >= 0 && yy < MB_H) {
            const float4 v = *reinterpret_cast<const float4*>(rp + x0);
            a[dy][1] = v.x; a[dy][2] = v.y; a[dy][3] = v.z; a[dy][4] = v.w;
            a[dy][0] = (x0 > 0)       ? rp[x0 - 1] : 0.0f;
            a[dy][5] = (x0 + 4 < MB_W) ? rp[x0 + 4] : 0.0f;
        } else {
            #pragma unroll
            for (int k = 0; k < 6; ++k) a[dy][k] = 0.0f;
        }
    }

    float res[4];
    #pragma unroll
    for (int j = 0; j < 4; ++j) {
        res[j] = median9(a[0][j], a[0][j + 1], a[0][j + 2],
                         a[1][j], a[1][j + 1], a[1][j + 2],
                         a[2][j], a[2][j + 1], a[2][j + 2]);
    }

    float4 o;
    o.x = res[0]; o.y = res[1]; o.z = res[2]; o.w = res[3];
    *reinterpret_cast<float4*>(out + (size_t)r * MB_W + x0) = o;
}

extern "C" void kernel_launch(void* const* d_in, const int* in_sizes, int n_in,
                              void* d_out, int out_size, void* d_ws, size_t ws_size,
                              hipStream_t stream) {
    const float* x = (const float*)d_in[0];
    float* out = (float*)d_out;
    const int threads = 256;
    const int blocks = MB_THREADS / threads; // 6144
    median_blur_kernel<<<blocks, threads, 0, stream>>>(x, out);
}

// Round 2
// 79.856 us; speedup vs baseline: 1.0052x; 1.0052x over previous
//
#include <hip/hip_runtime.h>

// Median blur 3x3, zero-padded, input (8,3,512,512) fp32 -> same shape.
// One thread computes 4 contiguous output pixels (float4 aligned).
// Median-of-9 via column-sort identity using gfx950 v_min3/v_med3/v_max3:
//   med9 = med3( max3(lo), med3(mid), min3(hi) )  over 3 sorted columns.

#define MB_W 512
#define MB_H 512
#define MB_PLANES (8 * 3)                 // B*C contiguous planes
#define MB_ROWS (MB_PLANES * MB_H)        // 12288 rows of 512 floats
#define MB_THREADS (MB_ROWS * (MB_W / 4)) // one float4 per thread

__device__ __forceinline__ float min3f(float a, float b, float c) {
    return fminf(fminf(a, b), c);         // fuses to v_min3_f32
}
__device__ __forceinline__ float max3f(float a, float b, float c) {
    return fmaxf(fmaxf(a, b), c);         // fuses to v_max3_f32
}
__device__ __forceinline__ float med3f(float a, float b, float c) {
    return __builtin_amdgcn_fmed3f(a, b, c); // v_med3_f32
}

__global__ __launch_bounds__(256) void median_blur_kernel(
        const float* __restrict__ in, float* __restrict__ out) {
    const int gid = blockIdx.x * blockDim.x + threadIdx.x;
    const int xq = gid & 127;      // x / 4 within row (W/4 = 128)
    const int r  = gid >> 7;       // global row index in [0, MB_ROWS)
    const int y  = r & (MB_H - 1); // row within plane
    const int x0 = xq << 2;        // first pixel x of this thread

    const float* rowc = in + (size_t)r * MB_W;

    // a0/a1/a2: rows y-1, y, y+1; index k=0 is x0-1, k=1..4 are x0..x0+3,
    // k=5 is x0+4 (zero-padded outside the plane).
    float a0[6], a1[6], a2[6];

    { // middle row: always in range
        const float4 v = *reinterpret_cast<const float4*>(rowc + x0);
        a1[1] = v.x; a1[2] = v.y; a1[3] = v.z; a1[4] = v.w;
        a1[0] = (x0 > 0)        ? rowc[x0 - 1] : 0.0f;
        a1[5] = (x0 + 4 < MB_W) ? rowc[x0 + 4] : 0.0f;
    }
    if (y > 0) {
        const float* rp = rowc - MB_W;
        const float4 v = *reinterpret_cast<const float4*>(rp + x0);
        a0[1] = v.x; a0[2] = v.y; a0[3] = v.z; a0[4] = v.w;
        a0[0] = (x0 > 0)        ? rp[x0 - 1] : 0.0f;
        a0[5] = (x0 + 4 < MB_W) ? rp[x0 + 4] : 0.0f;
    } else {
        #pragma unroll
        for (int k = 0; k < 6; ++k) a0[k] = 0.0f;
    }
    if (y < MB_H - 1) {
        const float* rp = rowc + MB_W;
        const float4 v = *reinterpret_cast<const float4*>(rp + x0);
        a2[1] = v.x; a2[2] = v.y; a2[3] = v.z; a2[4] = v.w;
        a2[0] = (x0 > 0)        ? rp[x0 - 1] : 0.0f;
        a2[5] = (x0 + 4 < MB_W) ? rp[x0 + 4] : 0.0f;
    } else {
        #pragma unroll
        for (int k = 0; k < 6; ++k) a2[k] = 0.0f;
    }

    // Sort each of the 6 columns (shared by up to 3 output pixels each).
    float lo[6], mi[6], hi[6];
    #pragma unroll
    for (int k = 0; k < 6; ++k) {
        lo[k] = min3f(a0[k], a1[k], a2[k]);
        mi[k] = med3f(a0[k], a1[k], a2[k]);
        hi[k] = max3f(a0[k], a1[k], a2[k]);
    }

    float res[4];
    #pragma unroll
    for (int j = 0; j < 4; ++j) {
        const float A = max3f(lo[j], lo[j + 1], lo[j + 2]);
        const float B = med3f(mi[j], mi[j + 1], mi[j + 2]);
        const float C = min3f(hi[j], hi[j + 1], hi[j + 2]);
        res[j] = med3f(A, B, C);
    }

    float4 o;
    o.x = res[0]; o.y = res[1]; o.z = res[2]; o.w = res[3];
    *reinterpret_cast<float4*>(out + (size_t)r * MB_W + x0) = o;
}

extern "C" void kernel_launch(void* const* d_in, const int* in_sizes, int n_in,
                              void* d_out, int out_size, void* d_ws, size_t ws_size,
                              hipStream_t stream) {
    const float* x = (const float*)d_in[0];
    float* out = (float*)d_out;
    const int threads = 256;
    const int blocks = MB_THREADS / threads; // 6144
    median_blur_kernel<<<blocks, threads, 0, stream>>>(x, out);
}

// Round 3
// 76.410 us; speedup vs baseline: 1.0506x; 1.0451x over previous
//
#include <hip/hip_runtime.h>

// Median blur 3x3, zero-padded, input (8,3,512,512) fp32 -> same shape.
// One thread computes a 4x4 pixel tile (4 rows x one float4), loading 6
// input rows once and reusing them across the 4 output rows.
// Median-of-9 via column-sort identity with gfx950 v_min3/v_med3/v_max3.

#define MB_W 512
#define MB_H 512
#define MB_PLANES (8 * 3)                 // B*C contiguous planes
#define MB_STRIPS (MB_H / 4)              // 128 4-row strips per plane
#define MB_XQ (MB_W / 4)                  // 128 float4 columns per row
#define MB_THREADS (MB_PLANES * MB_STRIPS * MB_XQ)  // 393216

__device__ __forceinline__ float min3f(float a, float b, float c) {
    return fminf(fminf(a, b), c);         // fuses to v_min3_f32
}
__device__ __forceinline__ float max3f(float a, float b, float c) {
    return fmaxf(fmaxf(a, b), c);         // fuses to v_max3_f32
}
__device__ __forceinline__ float med3f(float a, float b, float c) {
    return __builtin_amdgcn_fmed3f(a, b, c); // v_med3_f32
}

__global__ __launch_bounds__(256) void median_blur_kernel(
        const float* __restrict__ in, float* __restrict__ out) {
    const int gid  = blockIdx.x * blockDim.x + threadIdx.x;
    const int xq   = gid & (MB_XQ - 1);          // float4 column
    const int sg   = gid >> 7;                   // plane*128 + strip
    const int y0   = (sg & (MB_STRIPS - 1)) << 2;
    const int pl   = sg >> 7;
    const int x0   = xq << 2;

    const float* pb = in + (size_t)pl * (MB_H * MB_W);

    // a[dy][k]: input rows y0-1 .. y0+4; k=0 is x0-1, k=1..4 are x0..x0+3,
    // k=5 is x0+4. Zero-padded outside the plane.
    float a[6][6];
    #pragma unroll
    for (int dy = 0; dy < 6; ++dy) {
        const int yy = y0 + dy - 1;
        if (yy >= 0 && yy < MB_H) {              // only dy==0/5 can fail; wave-uniform
            const float* rp = pb + (size_t)yy * MB_W;
            const float4 v = *reinterpret_cast<const float4*>(rp + x0);
            a[dy][1] = v.x; a[dy][2] = v.y; a[dy][3] = v.z; a[dy][4] = v.w;
            a[dy][0] = (x0 > 0)        ? rp[x0 - 1] : 0.0f;
            a[dy][5] = (x0 + 4 < MB_W) ? rp[x0 + 4] : 0.0f;
        } else {
            #pragma unroll
            for (int k = 0; k < 6; ++k) a[dy][k] = 0.0f;
        }
    }

    float* ob = out + (size_t)pl * (MB_H * MB_W) + (size_t)y0 * MB_W + x0;
    #pragma unroll
    for (int w = 0; w < 4; ++w) {
        // Column sorts for window rows (y0+w-1, y0+w, y0+w+1).
        float lo[6], mi[6], hi[6];
        #pragma unroll
        for (int k = 0; k < 6; ++k) {
            lo[k] = min3f(a[w][k], a[w + 1][k], a[w + 2][k]);
            mi[k] = med3f(a[w][k], a[w + 1][k], a[w + 2][k]);
            hi[k] = max3f(a[w][k], a[w + 1][k], a[w + 2][k]);
        }
        float4 o;
        float r[4];
        #pragma unroll
        for (int j = 0; j < 4; ++j) {
            const float A = max3f(lo[j], lo[j + 1], lo[j + 2]);
            const float B = med3f(mi[j], mi[j + 1], mi[j + 2]);
            const float C = min3f(hi[j], hi[j + 1], hi[j + 2]);
            r[j] = med3f(A, B, C);
        }
        o.x = r[0]; o.y = r[1]; o.z = r[2]; o.w = r[3];
        *reinterpret_cast<float4*>(ob + (size_t)w * MB_W) = o;
    }
}

extern "C" void kernel_launch(void* const* d_in, const int* in_sizes, int n_in,
                              void* d_out, int out_size, void* d_ws, size_t ws_size,
                              hipStream_t stream) {
    const float* x = (const float*)d_in[0];
    float* out = (float*)d_out;
    const int threads = 256;
    const int blocks = MB_THREADS / threads; // 1536
    median_blur_kernel<<<blocks, threads, 0, stream>>>(x, out);
}

// Round 4
// 76.392 us; speedup vs baseline: 1.0508x; 1.0002x over previous
//
#include <hip/hip_runtime.h>

// Median blur 3x3, zero-padded, input (8,3,512,512) fp32 -> same shape.
// One WAVE covers a full 512-px row span: 64 lanes x 8 px (two float4s),
// strip of 4 output rows per wave. X-halo comes from __shfl with
// neighboring lanes (wave edges == plane edges -> zero pad); no scalar
// boundary loads at all. Median-of-9 via column-sort identity with
// gfx950 v_min3/v_med3/v_max3.

#define MB_W 512
#define MB_H 512
#define MB_PLANES (8 * 3)                 // B*C contiguous planes
#define MB_STRIPS (MB_H / 4)              // 128 4-row strips per plane
#define MB_THREADS (MB_PLANES * MB_STRIPS * 64)  // 196608 (3072 waves)

__device__ __forceinline__ float min3f(float a, float b, float c) {
    return fminf(fminf(a, b), c);         // fuses to v_min3_f32
}
__device__ __forceinline__ float max3f(float a, float b, float c) {
    return fmaxf(fmaxf(a, b), c);         // fuses to v_max3_f32
}
__device__ __forceinline__ float med3f(float a, float b, float c) {
    return __builtin_amdgcn_fmed3f(a, b, c); // v_med3_f32
}

__global__ __launch_bounds__(256, 3) void median_blur_kernel(
        const float* __restrict__ in, float* __restrict__ out) {
    const int gid  = blockIdx.x * blockDim.x + threadIdx.x;
    const int lane = gid & 63;
    const int sg   = gid >> 6;                   // global strip id (wave-uniform)
    const int y0   = (sg & (MB_STRIPS - 1)) << 2;
    const int pl   = sg >> 7;
    const int x0   = lane << 3;                  // 8 px per lane

    const float* pb = in + (size_t)pl * (MB_H * MB_W);

    // b[dy][k]: rows y0-1 .. y0+4, 8 px each. Zero outside the plane.
    float b[6][8];
    #pragma unroll
    for (int dy = 0; dy < 6; ++dy) {
        const int yy = y0 + dy - 1;
        if (yy >= 0 && yy < MB_H) {              // wave-uniform branch
            const float* rp = pb + (size_t)yy * MB_W + x0;
            const float4 v0 = *reinterpret_cast<const float4*>(rp);
            const float4 v1 = *reinterpret_cast<const float4*>(rp + 4);
            b[dy][0] = v0.x; b[dy][1] = v0.y; b[dy][2] = v0.z; b[dy][3] = v0.w;
            b[dy][4] = v1.x; b[dy][5] = v1.y; b[dy][6] = v1.z; b[dy][7] = v1.w;
        } else {
            #pragma unroll
            for (int k = 0; k < 8; ++k) b[dy][k] = 0.0f;
        }
    }

    // X-halo via intra-wave shuffles: x0-1 = prev lane's [7], x0+8 = next
    // lane's [0]. Wave edge == plane edge -> zero.
    float hl[6], hr[6];
    #pragma unroll
    for (int dy = 0; dy < 6; ++dy) {
        const float l = __shfl_up(b[dy][7], 1);
        const float r = __shfl_down(b[dy][0], 1);
        hl[dy] = (lane == 0)  ? 0.0f : l;
        hr[dy] = (lane == 63) ? 0.0f : r;
    }

    float* ob = out + (size_t)pl * (MB_H * MB_W) + (size_t)y0 * MB_W + x0;
    #pragma unroll
    for (int w = 0; w < 4; ++w) {
        // Column sorts over 10 columns (8 own + 2 halo) for rows w,w+1,w+2.
        float lo[10], mi[10], hi[10];
        lo[0] = min3f(hl[w], hl[w + 1], hl[w + 2]);
        mi[0] = med3f(hl[w], hl[w + 1], hl[w + 2]);
        hi[0] = max3f(hl[w], hl[w + 1], hl[w + 2]);
        #pragma unroll
        for (int k = 0; k < 8; ++k) {
            lo[k + 1] = min3f(b[w][k], b[w + 1][k], b[w + 2][k]);
            mi[k + 1] = med3f(b[w][k], b[w + 1][k], b[w + 2][k]);
            hi[k + 1] = max3f(b[w][k], b[w + 1][k], b[w + 2][k]);
        }
        lo[9] = min3f(hr[w], hr[w + 1], hr[w + 2]);
        mi[9] = med3f(hr[w], hr[w + 1], hr[w + 2]);
        hi[9] = max3f(hr[w], hr[w + 1], hr[w + 2]);

        float r[8];
        #pragma unroll
        for (int j = 0; j < 8; ++j) {
            const float A = max3f(lo[j], lo[j + 1], lo[j + 2]);
            const float B = med3f(mi[j], mi[j + 1], mi[j + 2]);
            const float C = min3f(hi[j], hi[j + 1], hi[j + 2]);
            r[j] = med3f(A, B, C);
        }
        float4 o0, o1;
        o0.x = r[0]; o0.y = r[1]; o0.z = r[2]; o0.w = r[3];
        o1.x = r[4]; o1.y = r[5]; o1.z = r[6]; o1.w = r[7];
        float* op = ob + (size_t)w * MB_W;
        *reinterpret_cast<float4*>(op)     = o0;
        *reinterpret_cast<float4*>(op + 4) = o1;
    }
}

extern "C" void kernel_launch(void* const* d_in, const int* in_sizes, int n_in,
                              void* d_out, int out_size, void* d_ws, size_t ws_size,
                              hipStream_t stream) {
    const float* x = (const float*)d_in[0];
    float* out = (float*)d_out;
    const int threads = 256;
    const int blocks = MB_THREADS / threads; // 768
    median_blur_kernel<<<blocks, threads, 0, stream>>>(x, out);
}